// Round 5
// baseline (130.383 us; speedup 1.0000x reference)
//
#include <hip/hip_runtime.h>

// EmbedDNF: B=128, IN_F=256, HID=512, OUT=128, E=8 (fp32, e innermost)
//
// impl = 1 - w*(1-xnor) = A + x*Bv ; A = 1 - w*s ; Bv = 2*w*s - w
// H[b,h,e]   = prod_i (A[i,h,e] + x[b,i,e]*Bv[i,h,e])
// out[b,o,e] = 1 - prod_h (1 - dw[h,o,e]*H[b,h,e])
//
// ws: H [512][128][8] fp32 (2 MB, h-major)
//
// R4 post-mortem: coalescing was fixed (FETCH=input size) but dur stuck at
// ~43 us with VALUBusy 12% -> serialized ~160-cyc L2-latency loads, no MLP.
// This version: explicit next/cur register pipelining (forces loads one full
// iteration ahead), 4 waves/SIMD occupancy, float4-over-e tiles to halve the
// load-instruction count.

#define LD4(p) (*(const float4*)(p))

static __device__ __forceinline__ float4 f4mul(float4 a, float4 b) {
    return make_float4(a.x*b.x, a.y*b.y, a.z*b.z, a.w*b.w);
}
static __device__ __forceinline__ float4 f4fma(float4 a, float4 b, float4 c) {
    return make_float4(fmaf(a.x,b.x,c.x), fmaf(a.y,b.y,c.y),
                       fmaf(a.z,b.z,c.z), fmaf(a.w,b.w,c.w));
}
static __device__ __forceinline__ float4 f4nfma1(float4 d, float4 h) {  // 1-d*h
    return make_float4(fmaf(-d.x,h.x,1.0f), fmaf(-d.y,h.y,1.0f),
                       fmaf(-d.z,h.z,1.0f), fmaf(-d.w,h.w,1.0f));
}

// ---------------------------------------------------------------------------
// Stage 1. Grid 256 = 16 hg (32 h, LOW bits -> ~1 MB w/s slice per XCD L2)
// x 16 bg (8 b). Block 1024 thr = 16 waves = 16 i-chunks of 16.
// Lane = eh(2 e-halves) x hl(32 h); thread tile 8b x 1h x 4e (float4).
// Per i: w,s = 2 contiguous 1 KB wave-loads; x = 8 single-line broadcasts.
// Depth-2 register pipeline; 16 i-partials merged by 4-round LDS tree (64 KB).
// ---------------------------------------------------------------------------
__global__ __launch_bounds__(1024, 4) void k_stage1(
    const float* __restrict__ in,   // [128][256][8]
    const float* __restrict__ cw,   // [256][512][8]
    const float* __restrict__ cs,   // [256][512][8]
    float* __restrict__ H)          // ws: [512][128][8]
{
    __shared__ float lds[8 * 2048];          // 64 KB (tree-combine buffer)
    const int t    = threadIdx.x;
    const int lane = t & 63;
    const int wv   = t >> 6;                 // i-chunk 0..15
    const int eh   = lane & 1;
    const int hl   = lane >> 1;              // 0..31
    const int hg   = blockIdx.x & 15;
    const int bg   = blockIdx.x >> 4;
    const int b0   = bg * 8;
    const int e0   = eh * 4;
    const int h    = hg * 32 + hl;

    const float* pw = cw + (wv * 16) * 4096 + h * 8 + e0;
    const float* ps = cs + (wv * 16) * 4096 + h * 8 + e0;
    const float* px = in + b0 * 2048 + (wv * 16) * 8 + e0;

    float4 acc[8];
    #pragma unroll
    for (int b = 0; b < 8; ++b) acc[b] = make_float4(1.f, 1.f, 1.f, 1.f);

    // prologue: iteration 0's w/s in flight before the loop
    float4 wn = LD4(pw);
    float4 sn = LD4(ps);

    #pragma unroll
    for (int ii = 0; ii < 16; ++ii) {
        const float4 wc = wn, sc = sn;
        if (ii < 15) {                        // issue next iteration's w/s NOW
            pw += 4096; ps += 4096;
            wn = LD4(pw); sn = LD4(ps);
        }
        float4 xv[8];
        #pragma unroll
        for (int b = 0; b < 8; ++b) xv[b] = LD4(px + b * 2048);
        px += 8;
        const float4 p  = f4mul(wc, sc);
        const float4 A  = make_float4(1.f - p.x, 1.f - p.y, 1.f - p.z, 1.f - p.w);
        const float4 Bv = make_float4(p.x + p.x - wc.x, p.y + p.y - wc.y,
                                      p.z + p.z - wc.z, p.w + p.w - wc.w);
        #pragma unroll
        for (int b = 0; b < 8; ++b)
            acc[b] = f4mul(acc[b], f4fma(xv[b], Bv, A));
    }

    // 4-round tree combine of the 16 wave partials (elementwise products)
    #pragma unroll
    for (int step = 8; step >= 1; step >>= 1) {
        if (wv >= step && wv < 2 * step) {
            #pragma unroll
            for (int b = 0; b < 8; ++b)
                *(float4*)&lds[(wv - step) * 2048 + b * 256 + hl * 8 + e0] = acc[b];
        }
        __syncthreads();
        if (wv < step) {
            #pragma unroll
            for (int b = 0; b < 8; ++b)
                acc[b] = f4mul(acc[b], LD4(&lds[wv * 2048 + b * 256 + hl * 8 + e0]));
        }
        __syncthreads();
    }

    if (wv == 0) {
        #pragma unroll
        for (int b = 0; b < 8; ++b)
            *(float4*)(H + (h * 128 + b0 + b) * 8 + e0) = acc[b];
    }
}

// ---------------------------------------------------------------------------
// Stage 2. Grid 256 = 16 bg (8 b, LOW bits -> H-slice locality) x 16 og (8 o).
// Block 512 thr = 8 waves = 8 h-chunks of 64. Lane = eh(2) x bl(8 b) x ol(4);
// thread tile 2o x 1b x 4e. Per h: 1 contiguous 256 B H load (bcast x4) +
// 2 dw loads. Depth-2 register pipeline; flat 8-way LDS combine.
// ---------------------------------------------------------------------------
__global__ __launch_bounds__(512, 4) void k_stage2(
    const float* __restrict__ dw,   // [512][128][8]
    const float* __restrict__ H,    // ws: [512][128][8]
    float* __restrict__ out)        // [128][128][8]
{
    __shared__ float lds[8 * 520];           // 16.6 KB
    const int t    = threadIdx.x;
    const int lane = t & 63;
    const int wv   = t >> 6;                 // h-chunk 0..7 (64 h each)
    const int eh   = lane & 1;
    const int bl   = (lane >> 1) & 7;
    const int ol   = lane >> 4;              // 0..3
    const int bg   = blockIdx.x & 15;
    const int og   = blockIdx.x >> 4;
    const int b    = bg * 8 + bl;
    const int o0   = og * 8 + ol * 2;
    const int e0   = eh * 4;

    const float* ph = H  + (wv * 64) * 1024 + b * 8 + e0;
    const float* pd = dw + (wv * 64) * 1024 + o0 * 8 + e0;

    float4 acc0 = make_float4(1.f, 1.f, 1.f, 1.f);
    float4 acc1 = acc0;

    float4 hn  = LD4(ph);
    float4 d0n = LD4(pd);
    float4 d1n = LD4(pd + 8);

    #pragma unroll 8
    for (int ii = 0; ii < 64; ++ii) {
        const float4 hc = hn, d0 = d0n, d1 = d1n;
        if (ii < 63) {
            ph += 1024; pd += 1024;
            hn = LD4(ph); d0n = LD4(pd); d1n = LD4(pd + 8);
        }
        acc0 = f4mul(acc0, f4nfma1(d0, hc));
        acc1 = f4mul(acc1, f4nfma1(d1, hc));
    }

    const int base = bl * 64 + (ol * 2) * 8 + e0;
    *(float4*)&lds[wv * 520 + base]     = acc0;
    *(float4*)&lds[wv * 520 + base + 8] = acc1;
    __syncthreads();

    // 512 outputs, 512 threads: idx = bl*64 + o_local*8 + e == t
    float m = lds[t];
    #pragma unroll
    for (int c = 1; c < 8; ++c) m *= lds[c * 520 + t];
    out[(bg * 8 + (t >> 6)) * 1024 + (og * 8 + ((t >> 3) & 7)) * 8 + (t & 7)] = 1.0f - m;
}

extern "C" void kernel_launch(void* const* d_in, const int* in_sizes, int n_in,
                              void* d_out, int out_size, void* d_ws, size_t ws_size,
                              hipStream_t stream)
{
    const float* in = (const float*)d_in[0];   // [128][256][8]
    const float* cw = (const float*)d_in[1];   // [256][512][8]
    const float* cs = (const float*)d_in[2];   // [256][512][8]
    const float* dw = (const float*)d_in[3];   // [512][128][8]
    float* outp = (float*)d_out;               // [128][128][8]
    float* H    = (float*)d_ws;                // 2 MB used

    k_stage1<<<256, 1024, 0, stream>>>(in, cw, cs, H);
    k_stage2<<<256, 512, 0, stream>>>(dw, H, outp);
}